// Round 5
// baseline (617.320 us; speedup 1.0000x reference)
//
#include <hip/hip_runtime.h>
#include <hip/hip_bf16.h>
#include <cstdint>
#include <cstddef>

// Grouped MoE FFN (fp32 in/out): h = gelu(x @ w1[e]^T + b1[e]); out = h @ w2[e]^T + b2[e]
// R5: global_load_lds dwordx4 staging (ladder m93->m97 rung), fp32 kept in LDS,
// fp32->bf16 cvt at fragment-read time. fp32 LDS rows = 128B = bank wrap, so
// 16B chunks are XOR-swizzled on the GLOBAL side (gll lets lanes pick their
// global source; LDS dest is fixed base+lane*16): physical chunk p of row R
// holds logical chunk p^(R&7). Frag reads spread ~2-way across banks (free).
// GEMM2's A (h) stays bf16 in d_ws with the verified m97 layout.

using bf16 = __hip_bfloat16;
typedef __attribute__((ext_vector_type(8))) short bf16x8;   // 8 bf16 = 4 VGPRs
typedef __attribute__((ext_vector_type(4))) float f32x4;

#define BM 128
#define BN 128
#define BK 32

__device__ __forceinline__ void gll16(const void* g, void* l) {
  // 16B/lane DMA; LDS dest = wave-uniform base + lane*16. Direct casts ->
  // addrspacecast (NOT via uintptr_t, which is a raw reinterpret).
  __builtin_amdgcn_global_load_lds(
      (const __attribute__((address_space(1))) void*)g,
      (__attribute__((address_space(3))) void*)l, 16, 0, 0);
}

__device__ __forceinline__ float gelu_f(float x) {
  // tanh-approx gelu (jax.nn.gelu default approximate=True)
  const float c0 = 0.7978845608028654f;  // sqrt(2/pi)
  const float c1 = 0.044715f;
  float u = c0 * (x + c1 * x * x * x);
  float t = 1.0f - 2.0f / (__expf(2.0f * u) + 1.0f);
  return 0.5f * x * (1.0f + t);
}

__device__ __forceinline__ bf16x8 cvt8(f32x4 lo, f32x4 hi) {
  bf16 cv[8];
#pragma unroll
  for (int q = 0; q < 4; ++q) {
    cv[q]     = __float2bfloat16(lo[q]);
    cv[q + 4] = __float2bfloat16(hi[q]);
  }
  return *(const bf16x8*)cv;
}

template <bool AF32>
__global__ __launch_bounds__(256) void grouped_gemm_bt(
    const void* __restrict__ Av,     // [M, K] row-major (fp32 if AF32 else bf16)
    const float* __restrict__ B,     // [E, N, K] row-major fp32 (B^T gemm)
    const float* __restrict__ bias,  // [E, N] fp32
    void* __restrict__ Cv,           // [M, N] output
    const int* __restrict__ counts,  // [E]
    int E, int N, int K, int c_is_bf16_gelu)  // 1: C=bf16 + gelu; 0: C=fp32
{
  constexpr int ABYTES = AF32 ? (BM * BK * 4) : (BM * BK * 2);
  __shared__ alignas(16) unsigned char smem[ABYTES + BN * BK * 4];
  unsigned char* Asm = smem;
  unsigned char* Bsm = smem + ABYTES;

  const int tid  = threadIdx.x;
  const int lane = tid & 63;
  const int wave = tid >> 6;
  const int m0 = blockIdx.y * BM;
  const int n0 = blockIdx.x * BN;

  // expert id for this row tile; block-uniform (no divergent barriers)
  int eid = 0;
  {
    long long cum = 0;
    for (int e = 0; e < E; ++e) { cum += counts[e]; if (m0 >= cum) eid = e + 1; }
  }

  const int wrow = (wave >> 1) * 64;   // wave tile 64x64 within 128x128
  const int wcol = (wave & 1) * 64;

  f32x4 acc[4][4] = {};

  if (eid < E) {
    const float* Bexp = B + (size_t)eid * (size_t)N * (size_t)K;

    // ---- staging pointers ----
    // fp32 swizzled issue (1KB = 8 rows x 128B): lane -> row lane>>3,
    // physical chunk lane&7, which must hold logical chunk (lane&7)^(lane>>3).
    const int srow8 = lane >> 3;
    const int scol  = ((lane & 7) ^ srow8) * 4;     // float col within row
    const float* gB = Bexp + (size_t)(n0 + wave * 32 + srow8) * K + scol;
    unsigned char* lB = Bsm + (wave * 32) * 128;    // +i*1024 per issue

    const float* gAf = nullptr;
    const bf16*  gAh = nullptr;
    unsigned char* lA;
    if constexpr (AF32) {
      gAf = (const float*)Av + (size_t)(m0 + wave * 32 + srow8) * K + scol;
      lA  = Asm + (wave * 32) * 128;
    } else {
      // m97 bf16 layout: issue = 16 rows x 64B; lane -> row lane>>2, col8 lane&3
      gAh = (const bf16*)Av + (size_t)(m0 + wave * 16 + (lane >> 2)) * K + (lane & 3) * 8;
      lA  = Asm + (wave * 16) * 64;
    }

    // ---- fragment-read pointers ----
    const int frow = lane & 15;          // m/n within 16
    const int s    = lane & 7;           // swizzle key: (R&7) with R=wrow+i*16+frow
    const int cb   = (lane >> 4) * 2;    // logical 16B chunk base (fk = (lane>>4)*8)
    const unsigned char* rB_lo = Bsm + ((wcol + frow) * 8 + (cb ^ s)) * 16;
    const unsigned char* rB_hi = Bsm + ((wcol + frow) * 8 + ((cb ^ 1) ^ s)) * 16;
    const unsigned char* rA_lo;
    const unsigned char* rA_hi = nullptr;
    if constexpr (AF32) {
      rA_lo = Asm + ((wrow + frow) * 8 + (cb ^ s)) * 16;
      rA_hi = Asm + ((wrow + frow) * 8 + ((cb ^ 1) ^ s)) * 16;
    } else {
      rA_lo = Asm + ((wrow + frow) * BK + (lane >> 4) * 8) * 2;
    }

    for (int kt = 0; kt < K; kt += BK) {
      // stage B (always fp32): 4 issues/wave
#pragma unroll
      for (int i = 0; i < 4; ++i)
        gll16(gB + (size_t)i * 8 * K + kt, lB + i * 1024);
      if constexpr (AF32) {
#pragma unroll
        for (int i = 0; i < 4; ++i)
          gll16(gAf + (size_t)i * 8 * K + kt, lA + i * 1024);
      } else {
        gll16(gAh + kt, lA);
        gll16(gAh + (size_t)64 * K + kt, lA + 4096);   // rows +64 -> 64*64B
      }
      __syncthreads();   // drains vmcnt -> staged tiles visible

      bf16x8 af[4], bfr[4];
#pragma unroll
      for (int i = 0; i < 4; ++i) {
        if constexpr (AF32) {
          f32x4 lo = *(const f32x4*)(rA_lo + i * 2048);   // 16 rows * 128B
          f32x4 hi = *(const f32x4*)(rA_hi + i * 2048);
          af[i] = cvt8(lo, hi);
        } else {
          af[i] = *(const bf16x8*)(rA_lo + i * 1024);     // 16 rows * 64B
        }
      }
#pragma unroll
      for (int j = 0; j < 4; ++j) {
        f32x4 lo = *(const f32x4*)(rB_lo + j * 2048);
        f32x4 hi = *(const f32x4*)(rB_hi + j * 2048);
        bfr[j] = cvt8(lo, hi);
      }

#pragma unroll
      for (int i = 0; i < 4; ++i)
#pragma unroll
        for (int j = 0; j < 4; ++j)
          acc[i][j] = __builtin_amdgcn_mfma_f32_16x16x32_bf16(af[i], bfr[j], acc[i][j], 0, 0, 0);

      __syncthreads();   // all reads done before next iter's staging writes
    }
  }

  // epilogue: C/D layout col=lane&15, row=(lane>>4)*4+reg (m89-verified)
  const int crow = (lane >> 4) * 4;
  const int ccol = lane & 15;
  const int do_gelu = c_is_bf16_gelu;

  if (eid < E) {
    float bv[4];
#pragma unroll
    for (int j = 0; j < 4; ++j)
      bv[j] = bias[(size_t)eid * N + n0 + wcol + j * 16 + ccol];
#pragma unroll
    for (int i = 0; i < 4; ++i) {
#pragma unroll
      for (int r = 0; r < 4; ++r) {
        size_t grow = (size_t)(m0 + wrow + i * 16 + crow + r);
#pragma unroll
        for (int j = 0; j < 4; ++j) {
          float v = acc[i][j][r] + bv[j];
          size_t idx = grow * N + n0 + wcol + j * 16 + ccol;
          if (do_gelu) ((bf16*)Cv)[idx] = __float2bfloat16(gelu_f(v));
          else         ((float*)Cv)[idx] = v;
        }
      }
    }
  } else {
    // tokens beyond cumsum(counts): write zeros
#pragma unroll
    for (int i = 0; i < 4; ++i) {
#pragma unroll
      for (int r = 0; r < 4; ++r) {
        size_t grow = (size_t)(m0 + wrow + i * 16 + crow + r);
#pragma unroll
        for (int j = 0; j < 4; ++j) {
          size_t idx = grow * N + n0 + wcol + j * 16 + ccol;
          if (do_gelu) ((bf16*)Cv)[idx] = __float2bfloat16(0.0f);
          else         ((float*)Cv)[idx] = 0.0f;
        }
      }
    }
  }
}

extern "C" void kernel_launch(void* const* d_in, const int* in_sizes, int n_in,
                              void* d_out, int out_size, void* d_ws, size_t ws_size,
                              hipStream_t stream) {
  const float* inp = (const float*)d_in[0];  // [T, D] fp32
  const float* w1  = (const float*)d_in[1];  // [E, H, D] fp32
  const float* b1  = (const float*)d_in[2];  // [E, H] fp32
  const float* w2  = (const float*)d_in[3];  // [E, D, H] fp32
  const float* b2  = (const float*)d_in[4];  // [E, D] fp32
  const int* cnt   = (const int*)d_in[5];    // [E] int32
  float* out = (float*)d_out;                // [T, D] fp32

  const int E = in_sizes[5];
  const int H = in_sizes[2] / E;             // b1 = E*H
  const int D = in_sizes[4] / E;             // b2 = E*D
  const int T = in_sizes[0] / D;             // inp = T*D

  bf16* h = (bf16*)d_ws;                     // [T, H] intermediate, bf16 (64 MB)

  dim3 blk(256);
  dim3 g1(H / BN, T / BM);
  grouped_gemm_bt<true><<<g1, blk, 0, stream>>>(inp, w1, b1, h, cnt, E, H, D, 1);
  dim3 g2(D / BN, T / BM);
  grouped_gemm_bt<false><<<g2, blk, 0, stream>>>(h, w2, b2, out, cnt, E, D, H, 0);
}